// Round 10
// baseline (553.123 us; speedup 1.0000x reference)
//
#include <hip/hip_runtime.h>
#include <hip/hip_cooperative_groups.h>

namespace cg = cooperative_groups;

#define BLOCKS  256
#define TPB     1024
#define WPB     16          // waves per block
#define NCELL   4096        // 16^3 Morton grid over [-4,4], width 0.5
#define NPMAX   256

__device__ inline unsigned spread4(unsigned v) {
    return (v & 1u) | ((v & 2u) << 2) | ((v & 4u) << 4) | ((v & 8u) << 6);
}
__device__ inline unsigned cellOf(float x, float y, float z) {
    int cx = (int)floorf((x + 4.0f) * 2.0f);
    int cy = (int)floorf((y + 4.0f) * 2.0f);
    int cz = (int)floorf((z + 4.0f) * 2.0f);
    cx = min(max(cx, 0), 15); cy = min(max(cy, 0), 15); cz = min(max(cz, 0), 15);
    return spread4((unsigned)cx) | (spread4((unsigned)cy) << 1) | (spread4((unsigned)cz) << 2);
}

// ---------------------------------------------------------------------------
// Single cooperative kernel: sort coords by cell (stable, atomic-free scatter
// via per-block histogram matrix + scans), then per-wave AABB particle cull +
// interaction loop. Excluded particles contribute exactly 0 and included ones
// are summed in ascending particle order -> output bitwise equals brute force.
// ---------------------------------------------------------------------------
__global__ __launch_bounds__(TPB, 4) void vortex_coop(
        const float* __restrict__ coord,
        const float* __restrict__ ppos, const float* __restrict__ pdir,
        const float* __restrict__ pint, const float* __restrict__ iraw,
        const float* __restrict__ rad,  const int* __restrict__ tmask,
        const int* __restrict__ tidxp,
        float* __restrict__ out, int N, int P, int T,
        unsigned* __restrict__ mt,        // [BLOCKS*NCELL] row-major per block
        unsigned* __restrict__ celltot,   // [NCELL]
        unsigned* __restrict__ cellbase,  // [NCELL]
        float4*   __restrict__ scoord) {  // [N]
    __shared__ float4 sparts[2 * NPMAX];              // 8 KB particle table
    __shared__ unsigned shist[NCELL];                 // 16 KB
    __shared__ unsigned short swidx[WPB * 256];       // 8 KB per-wave cand lists
    __shared__ int wtot[WPB];
    __shared__ int s_cnt;

    cg::grid_group grid = cg::this_grid();

    const int tid  = threadIdx.x;
    const int lane = tid & 63;
    const int wid  = tid >> 6;
    const int b    = blockIdx.x;
    const int gid  = b * TPB + tid;
    const bool valid = (gid < N);

    // ---------------- P0: per-block particle prep (redundant, deterministic)
    {
        const int t = *tidxp;
        bool active = false;
        float4 a, bb;
        if (tid < P) {
            const int p = tid;
            float m  = (float)tmask[p * T + t];
            float cl = fminf(fmaxf(iraw[p], 0.0f), 10.0f);
            float w  = sqrtf(cl + 1e-8f) * pint[p * T + t] * m;
            float r  = fmaxf(0.2f * (0.5f * rad[p] + 1.0f), 0.0f);
            active   = (w != 0.0f) && (r > 0.0f);
            if (active) {
                const float* pp = ppos + (size_t)(p * T + t) * 3;
                const float* pd = pdir + (size_t)(p * T + t) * 3;
                float A = w / (r * r * r * 40000.0f);
                a  = make_float4(pp[0], pp[1], pp[2],
                                 -1.442695040888963f / (2.0f * r * r));
                bb = make_float4(A * pd[0], A * pd[1], A * pd[2], 9.0f * r * r);
            }
        }
        unsigned long long bm = __ballot(active);
        int pre = __popcll(bm & ((1ull << lane) - 1ull));
        if (lane == 0) wtot[wid] = __popcll(bm);
        __syncthreads();
        int off = 0, tot = 0;
        #pragma unroll
        for (int w2 = 0; w2 < WPB; ++w2) {
            int c = wtot[w2];
            if (w2 < wid) off += c;
            tot += c;
        }
        if (active) {
            int pos = off + pre;
            sparts[2 * pos]     = a;
            sparts[2 * pos + 1] = bb;
        }
        if (tid == 0) s_cnt = tot;
    }

    // ---------------- P1: cell id + LDS hist (rank) + dump matrix row
    #pragma unroll
    for (int i = tid; i < NCELL; i += TPB) shist[i] = 0;
    __syncthreads();

    float cx = 0.f, cy = 0.f, cz = 0.f;
    unsigned cell = 0, rank = 0;
    if (valid) {
        cx = coord[3 * gid]; cy = coord[3 * gid + 1]; cz = coord[3 * gid + 2];
        cell = cellOf(cx, cy, cz);
        rank = atomicAdd(&shist[cell], 1u);
    }
    __syncthreads();
    #pragma unroll
    for (int i = tid; i < NCELL; i += TPB) mt[(size_t)b * NCELL + i] = shist[i];
    __threadfence();
    grid.sync();

    // ---------------- P2: per-cell column scan (stable per-block offsets)
    {
        const int c = b * WPB + wid;            // one wave per cell
        unsigned e0 = mt[(size_t)(lane * 4 + 0) * NCELL + c];
        unsigned e1 = mt[(size_t)(lane * 4 + 1) * NCELL + c];
        unsigned e2 = mt[(size_t)(lane * 4 + 2) * NCELL + c];
        unsigned e3 = mt[(size_t)(lane * 4 + 3) * NCELL + c];
        unsigned sum4 = e0 + e1 + e2 + e3;
        unsigned run = sum4;
        #pragma unroll
        for (int d = 1; d < 64; d <<= 1) {
            unsigned tt = __shfl_up(run, d);
            if (lane >= d) run += tt;
        }
        unsigned acc = run - sum4;              // exclusive
        mt[(size_t)(lane * 4 + 0) * NCELL + c] = acc; acc += e0;
        mt[(size_t)(lane * 4 + 1) * NCELL + c] = acc; acc += e1;
        mt[(size_t)(lane * 4 + 2) * NCELL + c] = acc; acc += e2;
        mt[(size_t)(lane * 4 + 3) * NCELL + c] = acc; acc += e3;
        if (lane == 63) celltot[c] = acc;
        __threadfence();
    }
    grid.sync();

    // ---------------- P3a: exclusive scan of cell totals (block 0, wave 0)
    if (b == 0 && tid < 64) {
        const int l = tid;
        unsigned s = 0;
        for (int i = 0; i < 64; ++i) s += celltot[l * 64 + i];
        unsigned run = s;
        #pragma unroll
        for (int d = 1; d < 64; d <<= 1) {
            unsigned tt = __shfl_up(run, d);
            if (l >= d) run += tt;
        }
        unsigned acc = run - s;
        for (int i = 0; i < 64; ++i) {
            cellbase[l * 64 + i] = acc;
            acc += celltot[l * 64 + i];
        }
        __threadfence();
    }
    grid.sync();

    // ---------------- P3b: stable scatter into cell-sorted order
    if (valid) {
        unsigned slot = cellbase[cell] + mt[(size_t)b * NCELL + cell] + rank;
        scoord[slot] = make_float4(cx, cy, cz, __int_as_float(gid));
    }
    __threadfence();
    grid.sync();

    // ---------------- P4: per-wave bbox cull + interaction loop
    const int cnt = s_cnt;
    const unsigned g0 = (unsigned)(b * WPB + wid);   // 0..4095
    const unsigned sw = __brev(g0) >> 20;            // 12-bit reverse scramble
    const size_t seg = (size_t)sw * 64 + lane;
    float4 sc = scoord[seg < (size_t)N ? seg : 0];
    const float qx = sc.x, qy = sc.y, qz = sc.z;
    const int orig = __float_as_int(sc.w);

    float mnx = qx, mxx = qx, mny = qy, mxy = qy, mnz = qz, mxz = qz;
    #pragma unroll
    for (int d = 32; d >= 1; d >>= 1) {
        mnx = fminf(mnx, __shfl_xor(mnx, d)); mxx = fmaxf(mxx, __shfl_xor(mxx, d));
        mny = fminf(mny, __shfl_xor(mny, d)); mxy = fmaxf(mxy, __shfl_xor(mxy, d));
        mnz = fminf(mnz, __shfl_xor(mnz, d)); mxz = fmaxf(mxz, __shfl_xor(mxz, d));
    }

    int C = 0;
    const int rounds = (cnt + 63) >> 6;
    for (int r = 0; r < rounds; ++r) {
        int p = r * 64 + lane;
        bool cand = false;
        if (p < cnt) {
            float4 pa = sparts[2 * p];
            float4 pb = sparts[2 * p + 1];
            float dx = fminf(fmaxf(pa.x, mnx), mxx) - pa.x;
            float dy = fminf(fmaxf(pa.y, mny), mxy) - pa.y;
            float dz = fminf(fmaxf(pa.z, mnz), mxz) - pa.z;
            float d2b = fmaf(dx, dx, fmaf(dy, dy, dz * dz));
            cand = d2b < pb.w;
        }
        unsigned long long bm = __ballot(cand);
        int pre = __popcll(bm & ((1ull << lane) - 1ull));
        if (cand) swidx[wid * 256 + C + pre] = (unsigned short)p;
        C += __popcll(bm);
    }

    float ax = 0.f, ay = 0.f, az = 0.f;
    for (int c2 = 0; c2 < C; ++c2) {
        int idx = swidx[wid * 256 + c2];         // wave-uniform broadcast
        float4 pa = sparts[2 * idx];
        float4 pb = sparts[2 * idx + 1];
        float lx = pa.x - qx, ly = pa.y - qy, lz = pa.z - qz;
        float d2 = fmaf(lx, lx, fmaf(ly, ly, lz * lz));
        float s  = __builtin_amdgcn_exp2f(d2 * pa.w) * __builtin_amdgcn_rsqf(d2);
        s = (d2 < pb.w) ? s : 0.0f;
        float crx = fmaf(ly, pb.z, -(lz * pb.y));
        float cry = fmaf(lz, pb.x, -(lx * pb.z));
        float crz = fmaf(lx, pb.y, -(ly * pb.x));
        ax = fmaf(s, crx, ax);
        ay = fmaf(s, cry, ay);
        az = fmaf(s, crz, az);
    }

    if (seg < (size_t)N) {
        out[3 * orig]     = ax;
        out[3 * orig + 1] = ay;
        out[3 * orig + 2] = az;
    }
}

extern "C" void kernel_launch(void* const* d_in, const int* in_sizes, int n_in,
                              void* d_out, int out_size, void* d_ws, size_t ws_size,
                              hipStream_t stream) {
    const float* coord = (const float*)d_in[0];
    const float* ppos  = (const float*)d_in[1];
    const float* pdir  = (const float*)d_in[2];
    const float* pint  = (const float*)d_in[3];
    const float* iraw  = (const float*)d_in[4];
    const float* rad   = (const float*)d_in[5];
    const int*   tmask = (const int*)d_in[6];
    const int*   tidx  = (const int*)d_in[7];
    float* out = (float*)d_out;

    int N = in_sizes[0] / 3;        // 262144
    int P = in_sizes[4];            // 256
    int T = in_sizes[3] / P;        // 8

    char* ws = (char*)d_ws;
    unsigned* mt       = (unsigned*)ws;                        // 4 MB
    unsigned* celltot  = (unsigned*)(ws + (4u << 20));         // 16 KB
    unsigned* cellbase = (unsigned*)(ws + (4u << 20) + 16384); // 16 KB
    float4*   scoord   = (float4*)(ws + (5u << 20));           // 4 MB

    void* kargs[] = {
        (void*)&coord, (void*)&ppos, (void*)&pdir, (void*)&pint,
        (void*)&iraw, (void*)&rad, (void*)&tmask, (void*)&tidx,
        (void*)&out, (void*)&N, (void*)&P, (void*)&T,
        (void*)&mt, (void*)&celltot, (void*)&cellbase, (void*)&scoord
    };
    hipLaunchCooperativeKernel((void*)vortex_coop, dim3(BLOCKS), dim3(TPB),
                               kargs, 0, stream);
}

// Round 11
// 23.500 us; speedup vs baseline: 23.5367x; 23.5367x over previous
//
#include <hip/hip_runtime.h>

#define THREADS 256   // 4 waves/block
#define CPT     2     // coords per thread -> 512 blocks, 2 blocks/CU
#define NPMAX   256   // max particles

typedef __attribute__((ext_vector_type(2))) float f32x2;

static __device__ __forceinline__ f32x2 v2(float v) { f32x2 r; r.x = v; r.y = v; return r; }
static __device__ __forceinline__ f32x2 fmav(f32x2 a, f32x2 b, f32x2 c) {
    return __builtin_elementwise_fma(a, b, c);   // -> v_pk_fma_f32
}

// ---------------------------------------------------------------------------
// Fused kernel (R4 structure, best so far) with a PACKED-FP32 inner loop:
// the two coords per thread are packed into f32x2 so most inner-loop VALU ops
// become v_pk_* (2 fp32 ops / issue on gfx950). Per-particle constants in two
// float4: pa = {px,py,pz, -log2e/(2r^2)}, pb = {A*dx,A*dy,A*dz, 9r^2}.
// inner: each = exp2(d2*pa.w) * rsq(d2) * cross(loc, pb.xyz)  if d2 < pb.w
// ---------------------------------------------------------------------------
__global__ __launch_bounds__(THREADS) void vortex_fused(
        const float* __restrict__ coord,
        const float* __restrict__ ppos,
        const float* __restrict__ pdir,
        const float* __restrict__ pint,
        const float* __restrict__ iraw,
        const float* __restrict__ rad,
        const int*   __restrict__ tmask,
        const int*   __restrict__ tidxp,
        float*       __restrict__ out,
        int N, int P, int T) {
    __shared__ float4 sp[2 * NPMAX];
    __shared__ int    wtot[THREADS / 64];
    __shared__ int    s_cnt;

    const int tid  = threadIdx.x;
    const int lane = tid & 63;
    const int wid  = tid >> 6;

    // ---- coord loads first so they overlap the prep work ----
    const int i0 = blockIdx.x * (THREADS * CPT) + tid;
    const int i1 = i0 + THREADS;
    const bool v0 = (i0 < N), v1 = (i1 < N);
    f32x2 cxv = v2(0.f), cyv = v2(0.f), czv = v2(0.f);
    if (v0) { cxv.x = coord[3 * i0]; cyv.x = coord[3 * i0 + 1]; czv.x = coord[3 * i0 + 2]; }
    if (v1) { cxv.y = coord[3 * i1]; cyv.y = coord[3 * i1 + 1]; czv.y = coord[3 * i1 + 2]; }

    // ---- per-particle prep + ballot compaction (deterministic order) ----
    const int t = *tidxp;
    bool active = false;
    float4 a, b;
    if (tid < P) {
        const int p = tid;
        float m  = (float)tmask[p * T + t];
        float cl = fminf(fmaxf(iraw[p], 0.0f), 10.0f);
        float w  = sqrtf(cl + 1e-8f) * pint[p * T + t] * m;
        float r  = fmaxf(0.2f * (0.5f * rad[p] + 1.0f), 0.0f);
        active   = (w != 0.0f) && (r > 0.0f);
        if (active) {
            const float* pp = ppos + (size_t)(p * T + t) * 3;
            const float* pd = pdir + (size_t)(p * T + t) * 3;
            float A = w / (r * r * r * 40000.0f);
            a = make_float4(pp[0], pp[1], pp[2], -1.442695040888963f / (2.0f * r * r));
            b = make_float4(A * pd[0], A * pd[1], A * pd[2], 9.0f * r * r);
        }
    }
    unsigned long long bm = __ballot(active);
    int pre = __popcll(bm & ((1ull << lane) - 1ull));
    if (lane == 0) wtot[wid] = __popcll(bm);
    __syncthreads();
    int off = 0, tot = 0;
    #pragma unroll
    for (int w2 = 0; w2 < THREADS / 64; ++w2) {
        int c = wtot[w2];
        if (w2 < wid) off += c;
        tot += c;
    }
    if (active) {
        int pos = off + pre;
        sp[2 * pos]     = a;
        sp[2 * pos + 1] = b;
    }
    if (tid == 0) s_cnt = tot;
    __syncthreads();
    const int cnt = s_cnt;   // uniform across block

    // ---- packed main loop: 2 LDS reads serve both packed coords ----
    f32x2 ax = v2(0.f), ay = v2(0.f), az = v2(0.f);
    #pragma unroll 4
    for (int p = 0; p < cnt; ++p) {
        const float4 pa = sp[2 * p];
        const float4 pb = sp[2 * p + 1];
        f32x2 lx = v2(pa.x) - cxv;
        f32x2 ly = v2(pa.y) - cyv;
        f32x2 lz = v2(pa.z) - czv;
        f32x2 d2 = fmav(lx, lx, fmav(ly, ly, lz * lz));
        f32x2 arg = d2 * v2(pa.w);
        f32x2 s;
        s.x = __builtin_amdgcn_exp2f(arg.x) * __builtin_amdgcn_rsqf(d2.x);
        s.y = __builtin_amdgcn_exp2f(arg.y) * __builtin_amdgcn_rsqf(d2.y);
        s.x = (d2.x < pb.w) ? s.x : 0.0f;
        s.y = (d2.y < pb.w) ? s.y : 0.0f;
        f32x2 crx = fmav(ly, v2(pb.z), -(lz * v2(pb.y)));
        f32x2 cry = fmav(lz, v2(pb.x), -(lx * v2(pb.z)));
        f32x2 crz = fmav(lx, v2(pb.y), -(ly * v2(pb.x)));
        ax = fmav(s, crx, ax);
        ay = fmav(s, cry, ay);
        az = fmav(s, crz, az);
    }

    if (v0) { out[3 * i0] = ax.x; out[3 * i0 + 1] = ay.x; out[3 * i0 + 2] = az.x; }
    if (v1) { out[3 * i1] = ax.y; out[3 * i1 + 1] = ay.y; out[3 * i1 + 2] = az.y; }
}

extern "C" void kernel_launch(void* const* d_in, const int* in_sizes, int n_in,
                              void* d_out, int out_size, void* d_ws, size_t ws_size,
                              hipStream_t stream) {
    const float* coord = (const float*)d_in[0];
    const float* ppos  = (const float*)d_in[1];
    const float* pdir  = (const float*)d_in[2];
    const float* pint  = (const float*)d_in[3];
    const float* iraw  = (const float*)d_in[4];
    const float* rad   = (const float*)d_in[5];
    const int*   tmask = (const int*)d_in[6];
    const int*   tidx  = (const int*)d_in[7];
    float* out = (float*)d_out;

    const int N = in_sizes[0] / 3;        // 262144 coords
    const int P = in_sizes[4];            // 256 particles (intensity_raw is (P,1))
    const int T = in_sizes[3] / P;        // 8 time steps (particle_intensity is (P,T,1))

    const int coordsPerBlock = THREADS * CPT;
    const int blocks = (N + coordsPerBlock - 1) / coordsPerBlock;
    hipLaunchKernelGGL(vortex_fused, dim3(blocks), dim3(THREADS), 0, stream,
                       coord, ppos, pdir, pint, iraw, rad, tmask, tidx, out, N, P, T);
}

// Round 12
// 23.442 us; speedup vs baseline: 23.5956x; 1.0025x over previous
//
#include <hip/hip_runtime.h>

#define THREADS 256   // 4 waves/block
#define CPT     4     // coords per thread -> 256 blocks, 1 block/CU
#define NPMAX   256   // max particles

typedef __attribute__((ext_vector_type(2))) float f32x2;

static __device__ __forceinline__ f32x2 v2(float v) { f32x2 r; r.x = v; r.y = v; return r; }
static __device__ __forceinline__ f32x2 fmav(f32x2 a, f32x2 b, f32x2 c) {
    return __builtin_elementwise_fma(a, b, c);   // -> v_pk_fma_f32
}

// ---------------------------------------------------------------------------
// Fused kernel, packed-fp32 inner loop, CPT=4: each thread owns 4 coords as
// TWO f32x2 packed groups, so the 2 LDS reads per particle are amortized over
// 4 coords (LDS pipe was the R11 limiter). 8 independent dep-chains per
// thread (2 groups x unroll) hide ds_read latency at 1 wave/SIMD.
// Per-particle constants: pa = {px,py,pz, -log2e/(2r^2)}, pb = {A*dx,A*dy,A*dz, 9r^2}.
// inner: each = exp2(d2*pa.w) * rsq(d2) * cross(loc, pb.xyz)  if d2 < pb.w
// ---------------------------------------------------------------------------
__global__ __launch_bounds__(THREADS) void vortex_fused(
        const float* __restrict__ coord,
        const float* __restrict__ ppos,
        const float* __restrict__ pdir,
        const float* __restrict__ pint,
        const float* __restrict__ iraw,
        const float* __restrict__ rad,
        const int*   __restrict__ tmask,
        const int*   __restrict__ tidxp,
        float*       __restrict__ out,
        int N, int P, int T) {
    __shared__ float4 sp[2 * NPMAX];
    __shared__ int    wtot[THREADS / 64];
    __shared__ int    s_cnt;

    const int tid  = threadIdx.x;
    const int lane = tid & 63;
    const int wid  = tid >> 6;

    // ---- coord loads first so they overlap the prep work ----
    const int i0 = blockIdx.x * (THREADS * CPT) + tid;
    const int i1 = i0 + THREADS;
    const int i2 = i0 + 2 * THREADS;
    const int i3 = i0 + 3 * THREADS;
    const bool v0 = (i0 < N), v1 = (i1 < N), v2_ = (i2 < N), v3 = (i3 < N);
    f32x2 cxA = v2(0.f), cyA = v2(0.f), czA = v2(0.f);   // coords 0,1
    f32x2 cxB = v2(0.f), cyB = v2(0.f), czB = v2(0.f);   // coords 2,3
    if (v0) { cxA.x = coord[3 * i0]; cyA.x = coord[3 * i0 + 1]; czA.x = coord[3 * i0 + 2]; }
    if (v1) { cxA.y = coord[3 * i1]; cyA.y = coord[3 * i1 + 1]; czA.y = coord[3 * i1 + 2]; }
    if (v2_) { cxB.x = coord[3 * i2]; cyB.x = coord[3 * i2 + 1]; czB.x = coord[3 * i2 + 2]; }
    if (v3) { cxB.y = coord[3 * i3]; cyB.y = coord[3 * i3 + 1]; czB.y = coord[3 * i3 + 2]; }

    // ---- per-particle prep + ballot compaction (deterministic order) ----
    const int t = *tidxp;
    bool active = false;
    float4 a, b;
    if (tid < P) {
        const int p = tid;
        float m  = (float)tmask[p * T + t];
        float cl = fminf(fmaxf(iraw[p], 0.0f), 10.0f);
        float w  = sqrtf(cl + 1e-8f) * pint[p * T + t] * m;
        float r  = fmaxf(0.2f * (0.5f * rad[p] + 1.0f), 0.0f);
        active   = (w != 0.0f) && (r > 0.0f);
        if (active) {
            const float* pp = ppos + (size_t)(p * T + t) * 3;
            const float* pd = pdir + (size_t)(p * T + t) * 3;
            float A = w / (r * r * r * 40000.0f);
            a = make_float4(pp[0], pp[1], pp[2], -1.442695040888963f / (2.0f * r * r));
            b = make_float4(A * pd[0], A * pd[1], A * pd[2], 9.0f * r * r);
        }
    }
    unsigned long long bm = __ballot(active);
    int pre = __popcll(bm & ((1ull << lane) - 1ull));
    if (lane == 0) wtot[wid] = __popcll(bm);
    __syncthreads();
    int off = 0, tot = 0;
    #pragma unroll
    for (int w2 = 0; w2 < THREADS / 64; ++w2) {
        int c = wtot[w2];
        if (w2 < wid) off += c;
        tot += c;
    }
    if (active) {
        int pos = off + pre;
        sp[2 * pos]     = a;
        sp[2 * pos + 1] = b;
    }
    if (tid == 0) s_cnt = tot;
    __syncthreads();
    const int cnt = s_cnt;   // uniform across block

    // ---- packed main loop: 2 LDS reads serve 4 coords ----
    f32x2 axA = v2(0.f), ayA = v2(0.f), azA = v2(0.f);
    f32x2 axB = v2(0.f), ayB = v2(0.f), azB = v2(0.f);
    #pragma unroll 4
    for (int p = 0; p < cnt; ++p) {
        const float4 pa = sp[2 * p];
        const float4 pb = sp[2 * p + 1];
        {   // group A (coords 0,1)
            f32x2 lx = v2(pa.x) - cxA;
            f32x2 ly = v2(pa.y) - cyA;
            f32x2 lz = v2(pa.z) - czA;
            f32x2 d2 = fmav(lx, lx, fmav(ly, ly, lz * lz));
            f32x2 arg = d2 * v2(pa.w);
            f32x2 s;
            s.x = __builtin_amdgcn_exp2f(arg.x) * __builtin_amdgcn_rsqf(d2.x);
            s.y = __builtin_amdgcn_exp2f(arg.y) * __builtin_amdgcn_rsqf(d2.y);
            s.x = (d2.x < pb.w) ? s.x : 0.0f;
            s.y = (d2.y < pb.w) ? s.y : 0.0f;
            f32x2 crx = fmav(ly, v2(pb.z), -(lz * v2(pb.y)));
            f32x2 cry = fmav(lz, v2(pb.x), -(lx * v2(pb.z)));
            f32x2 crz = fmav(lx, v2(pb.y), -(ly * v2(pb.x)));
            axA = fmav(s, crx, axA);
            ayA = fmav(s, cry, ayA);
            azA = fmav(s, crz, azA);
        }
        {   // group B (coords 2,3)
            f32x2 lx = v2(pa.x) - cxB;
            f32x2 ly = v2(pa.y) - cyB;
            f32x2 lz = v2(pa.z) - czB;
            f32x2 d2 = fmav(lx, lx, fmav(ly, ly, lz * lz));
            f32x2 arg = d2 * v2(pa.w);
            f32x2 s;
            s.x = __builtin_amdgcn_exp2f(arg.x) * __builtin_amdgcn_rsqf(d2.x);
            s.y = __builtin_amdgcn_exp2f(arg.y) * __builtin_amdgcn_rsqf(d2.y);
            s.x = (d2.x < pb.w) ? s.x : 0.0f;
            s.y = (d2.y < pb.w) ? s.y : 0.0f;
            f32x2 crx = fmav(ly, v2(pb.z), -(lz * v2(pb.y)));
            f32x2 cry = fmav(lz, v2(pb.x), -(lx * v2(pb.z)));
            f32x2 crz = fmav(lx, v2(pb.y), -(ly * v2(pb.x)));
            axB = fmav(s, crx, axB);
            ayB = fmav(s, cry, ayB);
            azB = fmav(s, crz, azB);
        }
    }

    if (v0) { out[3 * i0] = axA.x; out[3 * i0 + 1] = ayA.x; out[3 * i0 + 2] = azA.x; }
    if (v1) { out[3 * i1] = axA.y; out[3 * i1 + 1] = ayA.y; out[3 * i1 + 2] = azA.y; }
    if (v2_) { out[3 * i2] = axB.x; out[3 * i2 + 1] = ayB.x; out[3 * i2 + 2] = azB.x; }
    if (v3) { out[3 * i3] = axB.y; out[3 * i3 + 1] = ayB.y; out[3 * i3 + 2] = azB.y; }
}

extern "C" void kernel_launch(void* const* d_in, const int* in_sizes, int n_in,
                              void* d_out, int out_size, void* d_ws, size_t ws_size,
                              hipStream_t stream) {
    const float* coord = (const float*)d_in[0];
    const float* ppos  = (const float*)d_in[1];
    const float* pdir  = (const float*)d_in[2];
    const float* pint  = (const float*)d_in[3];
    const float* iraw  = (const float*)d_in[4];
    const float* rad   = (const float*)d_in[5];
    const int*   tmask = (const int*)d_in[6];
    const int*   tidx  = (const int*)d_in[7];
    float* out = (float*)d_out;

    const int N = in_sizes[0] / 3;        // 262144 coords
    const int P = in_sizes[4];            // 256 particles (intensity_raw is (P,1))
    const int T = in_sizes[3] / P;        // 8 time steps (particle_intensity is (P,T,1))

    const int coordsPerBlock = THREADS * CPT;
    const int blocks = (N + coordsPerBlock - 1) / coordsPerBlock;
    hipLaunchKernelGGL(vortex_fused, dim3(blocks), dim3(THREADS), 0, stream,
                       coord, ppos, pdir, pint, iraw, rad, tmask, tidx, out, N, P, T);
}